// Round 1
// baseline (923.139 us; speedup 1.0000x reference)
//
#include <hip/hip_runtime.h>
#include <hip/hip_bf16.h>

// ---- types ----
typedef __bf16 bf16x8 __attribute__((ext_vector_type(8)));
typedef float  f32x4  __attribute__((ext_vector_type(4)));
typedef unsigned short u16;
typedef u16 u16x8 __attribute__((ext_vector_type(8)));

// fp32 -> bf16 round-to-nearest-even
__device__ __forceinline__ u16 f2bf(float f) {
    unsigned u = __float_as_uint(f);
    u += 0x7FFFu + ((u >> 16) & 1u);
    return (u16)(u >> 16);
}
__device__ __forceinline__ float bf2f(u16 s) {
    return __uint_as_float(((unsigned)s) << 16);
}

// Stage 64x256 fp32 row-major tile -> bf16 LDS [64][256], XOR-swizzled rows.
// byte addr = row*512 + (colByte ^ ((row&7)<<4))  -- keeps 16B alignment.
__device__ __forceinline__ void stage_tile(const float* __restrict__ src, char* buf, int t) {
#pragma unroll
    for (int i = 0; i < 8; ++i) {
        int flat = i * 2048 + t * 8;
        float4 a = *(const float4*)(src + flat);
        float4 b = *(const float4*)(src + flat + 4);
        int row  = flat >> 8;
        int colb = (flat & 255) * 2;
        u16x8 v;
        v[0]=f2bf(a.x); v[1]=f2bf(a.y); v[2]=f2bf(a.z); v[3]=f2bf(a.w);
        v[4]=f2bf(b.x); v[5]=f2bf(b.y); v[6]=f2bf(b.z); v[7]=f2bf(b.w);
        *(u16x8*)(buf + row*512 + (colb ^ ((row & 7) << 4))) = v;
    }
}

// 64x256 @ 256x256 GEMM: A from swizzled LDS, B-fragments pre-packed in global.
// Wave w owns output cols [64w, 64w+64). acc[mt][nt]: C[mt*16+(l>>4)*4+r][w*64+nt*16+(l&15)]
__device__ __forceinline__ void gemm_tile(const char* buf, const u16* __restrict__ WB,
                                          int w, int l, f32x4 acc[4][4]) {
#pragma unroll
    for (int mt = 0; mt < 4; mt++)
#pragma unroll
        for (int nt = 0; nt < 4; nt++) acc[mt][nt] = (f32x4){0.f,0.f,0.f,0.f};
#pragma unroll
    for (int ks = 0; ks < 8; ks++) {
        bf16x8 bfrag[4];
#pragma unroll
        for (int nt = 0; nt < 4; nt++)
            bfrag[nt] = *(const bf16x8*)(WB + (((ks*16) + (w*4 + nt))*64 + l)*8);
        bf16x8 afrag[4];
#pragma unroll
        for (int mt = 0; mt < 4; mt++) {
            int row  = mt*16 + (l & 15);
            int colb = ks*64 + ((l >> 4) << 4);
            afrag[mt] = *(const bf16x8*)(buf + row*512 + (colb ^ ((row & 7) << 4)));
        }
#pragma unroll
        for (int mt = 0; mt < 4; mt++)
#pragma unroll
            for (int nt = 0; nt < 4; nt++)
                acc[mt][nt] = __builtin_amdgcn_mfma_f32_16x16x32_bf16(
                    afrag[mt], bfrag[nt], acc[mt][nt], 0, 0, 0);
    }
}

// ---- prep: repack weights into bf16 MFMA-B-fragment layouts ----
// WnB/WaB: 65536 entries, idx = ((ks*16+ntg)*64+l)*8+j  -> W[n*256+k], n=ntg*16+(l&15), k=ks*32+(l>>4)*8+j
// WqF/WkF: 8192 entries,  idx = ((h*2+nt)*64+l)*8+j     -> W[h*1024 + n*32 + e], n=nt*16+(l&15), e=(l>>4)*8+j
__global__ void k_prep(const float* __restrict__ Wa, const float* __restrict__ Wn,
                       const float* __restrict__ Wq, const float* __restrict__ Wk,
                       u16* __restrict__ WaB, u16* __restrict__ WnB,
                       u16* __restrict__ WqF, u16* __restrict__ WkF) {
    int i = blockIdx.x * 256 + threadIdx.x;
    int j = i & 7, l = (i >> 3) & 63, ntg = (i >> 9) & 15, ks = i >> 13;
    int n = ntg*16 + (l & 15), k = ks*32 + ((l >> 4) << 3) + j;
    WaB[i] = f2bf(Wa[n*256 + k]);
    WnB[i] = f2bf(Wn[n*256 + k]);
    if (i < 8192) {
        int nt = (i >> 9) & 1, h = i >> 10;
        int n2 = nt*16 + (l & 15), e = ((l >> 4) << 3) + j;
        WqF[i] = f2bf(Wq[h*1024 + n2*32 + e]);
        WkF[i] = f2bf(Wk[h*1024 + n2*32 + e]);
    }
}

// ---- anchor kernel: h_anchor = LN(x_anchor@Wa^T+b)+ve ; q = (h_anchor_h@Wq_h^T)/sqrt(32); gs=softplus ----
__global__ __launch_bounds__(256, 3) void k_anchor(
    const float* __restrict__ xa, const float* __restrict__ gl,
    const float* __restrict__ b_anc, const float* __restrict__ g_anc,
    const float* __restrict__ be_anc, const float* __restrict__ ve,
    const float* __restrict__ Wgeom, const float* __restrict__ bgeom,
    const u16* __restrict__ WaB, const u16* __restrict__ WqF,
    float* __restrict__ ha, float* __restrict__ qws, float* __restrict__ gsws) {
    __shared__ __align__(16) char smem[32768 + 2048];
    const int t = threadIdx.x, w = t >> 6, l = t & 63;
    const int b0 = blockIdx.x * 64;

    stage_tile(xa + (size_t)b0 * 256, smem, t);
    __syncthreads();

    f32x4 acc[4][4];
    gemm_tile(smem, WaB, w, l, acc);

    float bn[4];
#pragma unroll
    for (int nt = 0; nt < 4; nt++) bn[nt] = b_anc[w*64 + nt*16 + (l & 15)];
#pragma unroll
    for (int mt = 0; mt < 4; mt++)
#pragma unroll
        for (int nt = 0; nt < 4; nt++)
#pragma unroll
            for (int r = 0; r < 4; r++) acc[mt][nt][r] += bn[nt];

    float2* PART = (float2*)(smem + 32768);
#pragma unroll
    for (int mt = 0; mt < 4; mt++)
#pragma unroll
        for (int r = 0; r < 4; r++) {
            float s  = acc[mt][0][r] + acc[mt][1][r] + acc[mt][2][r] + acc[mt][3][r];
            float qq = acc[mt][0][r]*acc[mt][0][r] + acc[mt][1][r]*acc[mt][1][r]
                     + acc[mt][2][r]*acc[mt][2][r] + acc[mt][3][r]*acc[mt][3][r];
#pragma unroll
            for (int m2 = 1; m2 < 16; m2 <<= 1) { s += __shfl_xor(s, m2); qq += __shfl_xor(qq, m2); }
            if ((l & 15) == 0) PART[w*64 + mt*16 + ((l >> 4) << 2) + r] = make_float2(s, qq);
        }
    __syncthreads();

    float gg[4], bb2[4], vv[4];
#pragma unroll
    for (int nt = 0; nt < 4; nt++) {
        int col = w*64 + nt*16 + (l & 15);
        gg[nt] = g_anc[col]; bb2[nt] = be_anc[col];
        vv[nt] = ve[((nt & 1) << 4) + (l & 15)];
    }
#pragma unroll
    for (int mt = 0; mt < 4; mt++)
#pragma unroll
        for (int r = 0; r < 4; r++) {
            int row = mt*16 + ((l >> 4) << 2) + r;
            float2 p0 = PART[row], p1 = PART[64+row], p2 = PART[128+row], p3 = PART[192+row];
            float mean = (p0.x+p1.x+p2.x+p3.x) * (1.f/256.f);
            float var  = (p0.y+p1.y+p2.y+p3.y) * (1.f/256.f) - mean*mean;
            float rs   = rsqrtf(var + 1e-5f);
#pragma unroll
            for (int nt = 0; nt < 4; nt++) {
                int col = w*64 + nt*16 + (l & 15);
                float x = (acc[mt][nt][r] - mean)*rs*gg[nt] + bb2[nt] + vv[nt];
                ha[(size_t)(b0+row)*256 + col] = x;
                *(u16*)(smem + row*512 + ((col*2) ^ ((row & 7) << 4))) = f2bf(x);
            }
        }
    __syncthreads();

    // q projection (2 heads/wave), K=32 single MFMA step
#pragma unroll
    for (int hh = 0; hh < 2; hh++) {
        int h = 2*w + hh;
        bf16x8 af[4];
#pragma unroll
        for (int mt = 0; mt < 4; mt++) {
            int row = mt*16 + (l & 15);
            int colb = h*64 + ((l >> 4) << 4);
            af[mt] = *(const bf16x8*)(smem + row*512 + (colb ^ ((row & 7) << 4)));
        }
        bf16x8 bf0 = *(const bf16x8*)(WqF + ((h*2 + 0)*64 + l)*8);
        bf16x8 bf1 = *(const bf16x8*)(WqF + ((h*2 + 1)*64 + l)*8);
        f32x4 qa[4][2];
#pragma unroll
        for (int mt = 0; mt < 4; mt++) {
            qa[mt][0] = (f32x4){0.f,0.f,0.f,0.f};
            qa[mt][1] = (f32x4){0.f,0.f,0.f,0.f};
            qa[mt][0] = __builtin_amdgcn_mfma_f32_16x16x32_bf16(af[mt], bf0, qa[mt][0], 0,0,0);
            qa[mt][1] = __builtin_amdgcn_mfma_f32_16x16x32_bf16(af[mt], bf1, qa[mt][1], 0,0,0);
        }
#pragma unroll
        for (int mt = 0; mt < 4; mt++)
#pragma unroll
            for (int nt = 0; nt < 2; nt++)
#pragma unroll
                for (int r = 0; r < 4; r++) {
                    int row = mt*16 + ((l >> 4) << 2) + r;
                    int d = nt*16 + (l & 15);
                    qws[(size_t)(b0+row)*256 + h*32 + d] = qa[mt][nt][r] * 0.17677669529663687f;
                }
    }

    // geom_scale = softplus(g_local @ Wg^T + bg)
    for (int task = t; task < 512; task += 256) {
        int row = task >> 3, h = task & 7;
        const float* g = gl + (size_t)(b0+row)*32;
        float x = bgeom[h];
#pragma unroll
        for (int e = 0; e < 32; e++) x += g[e] * Wgeom[h*32 + e];
        gsws[(size_t)(b0+row)*8 + h] = (x > 20.f) ? x : log1pf(__expf(x));
    }
}

// ---- main kernel: per batch row, fully fused neighbor path ----
#define SM_AT 32768          // 2048 B: attn [8][64] f32 (overlays PART)
#define SM_Z  (32768+2048)   // 1024 B
#define SM_PO (32768+3072)   // 1024 B
#define SM_EL (32768+4096)   // 256  B: log(ew+eps)
__global__ __launch_bounds__(256, 3) void k_main(
    const float* __restrict__ xn, const float* __restrict__ ew,
    const float* __restrict__ b_nei, const float* __restrict__ g_nei,
    const float* __restrict__ be_nei,
    const float* __restrict__ Wv, const float* __restrict__ Wo,
    const u16* __restrict__ WnB, const u16* __restrict__ WkF,
    const float* __restrict__ ha, const float* __restrict__ qws,
    const float* __restrict__ gsws, float* __restrict__ outp, int Btot) {
    __shared__ __align__(16) char smem[37120];
    const int t = threadIdx.x, w = t >> 6, l = t & 63;
    const int b = blockIdx.x;

    stage_tile(xn + (size_t)b * 16384, smem, t);
    if (t < 64) ((float*)(smem + SM_EL))[t] = __logf(ew[(size_t)b*64 + t] + 1e-6f);
    __syncthreads();

    f32x4 acc[4][4];
    gemm_tile(smem, WnB, w, l, acc);

    float bn[4];
#pragma unroll
    for (int nt = 0; nt < 4; nt++) bn[nt] = b_nei[w*64 + nt*16 + (l & 15)];
#pragma unroll
    for (int mt = 0; mt < 4; mt++)
#pragma unroll
        for (int nt = 0; nt < 4; nt++)
#pragma unroll
            for (int r = 0; r < 4; r++) acc[mt][nt][r] += bn[nt];

    float2* PART = (float2*)(smem + SM_AT);
#pragma unroll
    for (int mt = 0; mt < 4; mt++)
#pragma unroll
        for (int r = 0; r < 4; r++) {
            float s  = acc[mt][0][r] + acc[mt][1][r] + acc[mt][2][r] + acc[mt][3][r];
            float qq = acc[mt][0][r]*acc[mt][0][r] + acc[mt][1][r]*acc[mt][1][r]
                     + acc[mt][2][r]*acc[mt][2][r] + acc[mt][3][r]*acc[mt][3][r];
#pragma unroll
            for (int m2 = 1; m2 < 16; m2 <<= 1) { s += __shfl_xor(s, m2); qq += __shfl_xor(qq, m2); }
            if ((l & 15) == 0) PART[w*64 + mt*16 + ((l >> 4) << 2) + r] = make_float2(s, qq);
        }
    __syncthreads();

    float gg[4], bb2[4];
#pragma unroll
    for (int nt = 0; nt < 4; nt++) {
        int col = w*64 + nt*16 + (l & 15);
        gg[nt] = g_nei[col]; bb2[nt] = be_nei[col];
    }
#pragma unroll
    for (int mt = 0; mt < 4; mt++)
#pragma unroll
        for (int r = 0; r < 4; r++) {
            int row = mt*16 + ((l >> 4) << 2) + r;
            float2 p0 = PART[row], p1 = PART[64+row], p2 = PART[128+row], p3 = PART[192+row];
            float mean = (p0.x+p1.x+p2.x+p3.x) * (1.f/256.f);
            float var  = (p0.y+p1.y+p2.y+p3.y) * (1.f/256.f) - mean*mean;
            float rs   = rsqrtf(var + 1e-5f);
#pragma unroll
            for (int nt = 0; nt < 4; nt++) {
                int col = w*64 + nt*16 + (l & 15);
                float x = (acc[mt][nt][r] - mean)*rs*gg[nt] + bb2[nt];
                *(u16*)(smem + row*512 + ((col*2) ^ ((row & 7) << 4))) = f2bf(x);
            }
        }
    __syncthreads();

    // K projection (in-register) + scores + softmax; 2 heads per wave
    const float* EL = (const float*)(smem + SM_EL);
    float* AT = (float*)(smem + SM_AT);
#pragma unroll
    for (int hh = 0; hh < 2; hh++) {
        int h = 2*w + hh;
        bf16x8 af[4];
#pragma unroll
        for (int mt = 0; mt < 4; mt++) {
            int row = mt*16 + (l & 15);
            int colb = h*64 + ((l >> 4) << 4);
            af[mt] = *(const bf16x8*)(smem + row*512 + (colb ^ ((row & 7) << 4)));
        }
        bf16x8 bf0 = *(const bf16x8*)(WkF + ((h*2 + 0)*64 + l)*8);
        bf16x8 bf1 = *(const bf16x8*)(WkF + ((h*2 + 1)*64 + l)*8);
        f32x4 ka0[4], ka1[4];
#pragma unroll
        for (int mt = 0; mt < 4; mt++) {
            ka0[mt] = (f32x4){0.f,0.f,0.f,0.f};
            ka1[mt] = (f32x4){0.f,0.f,0.f,0.f};
            ka0[mt] = __builtin_amdgcn_mfma_f32_16x16x32_bf16(af[mt], bf0, ka0[mt], 0,0,0);
            ka1[mt] = __builtin_amdgcn_mfma_f32_16x16x32_bf16(af[mt], bf1, ka1[mt], 0,0,0);
        }
        float qv0 = qws[(size_t)b*256 + h*32 + (l & 15)];
        float qv1 = qws[(size_t)b*256 + h*32 + 16 + (l & 15)];
        float gsv = gsws[(size_t)b*8 + h];
        float ps[4][4];
#pragma unroll
        for (int mt = 0; mt < 4; mt++)
#pragma unroll
            for (int r = 0; r < 4; r++) {
                float s = ka0[mt][r]*qv0 + ka1[mt][r]*qv1;
#pragma unroll
                for (int m2 = 1; m2 < 16; m2 <<= 1) s += __shfl_xor(s, m2);
                ps[mt][r] = s + gsv * EL[mt*16 + ((l >> 4) << 2) + r];
            }
        float mx = -1e30f;
#pragma unroll
        for (int mt = 0; mt < 4; mt++)
#pragma unroll
            for (int r = 0; r < 4; r++) mx = fmaxf(mx, ps[mt][r]);
        mx = fmaxf(mx, __shfl_xor(mx, 16));
        mx = fmaxf(mx, __shfl_xor(mx, 32));
        float ex[4][4]; float sm = 0.f;
#pragma unroll
        for (int mt = 0; mt < 4; mt++)
#pragma unroll
            for (int r = 0; r < 4; r++) { ex[mt][r] = __expf(ps[mt][r] - mx); sm += ex[mt][r]; }
        sm += __shfl_xor(sm, 16);
        sm += __shfl_xor(sm, 32);
        float inv = 1.f / sm;
        if ((l & 15) == 0) {
#pragma unroll
            for (int mt = 0; mt < 4; mt++) {
                float4 v4 = make_float4(ex[mt][0]*inv, ex[mt][1]*inv, ex[mt][2]*inv, ex[mt][3]*inv);
                *(float4*)(AT + h*64 + mt*16 + ((l >> 4) << 2)) = v4;
            }
        }
    }
    __syncthreads();

    // write attn output + z = attn^T @ h_nei (per head column slice)
    const size_t ATT_OFF = (size_t)Btot * 256;
#pragma unroll
    for (int i = t; i < 512; i += 256) outp[ATT_OFF + (size_t)b*512 + i] = AT[i];

    int h = t >> 5, e2 = t & 31;
    float z = 0.f;
#pragma unroll
    for (int k = 0; k < 64; k++) {
        float a = AT[h*64 + k];
        u16 hv = *(const u16*)(smem + k*512 + (((h*64) + (e2 << 1)) ^ ((k & 7) << 4)));
        z += a * bf2f(hv);
    }
    ((float*)(smem + SM_Z))[t] = z;
    __syncthreads();

    float po = 0.f;
    {
        const float* wv = Wv + h*1024 + (t & 31)*32;
        const float* zz = (const float*)(smem + SM_Z) + h*32;
#pragma unroll
        for (int e = 0; e < 32; e++) po += wv[e] * zz[e];
    }
    ((float*)(smem + SM_PO))[t] = po;
    __syncthreads();

    float o = 0.f;
    {
        const float* wo = Wo + h*1024 + (t & 31)*32;
        const float* pp = (const float*)(smem + SM_PO) + h*32;
#pragma unroll
        for (int d = 0; d < 32; d++) o += wo[d] * pp[d];
    }
    o += ha[(size_t)b*256 + t];
    outp[(size_t)b*256 + t] = o;
}

extern "C" void kernel_launch(void* const* d_in, const int* in_sizes, int n_in,
                              void* d_out, int out_size, void* d_ws, size_t ws_size,
                              hipStream_t stream) {
    const float* xa  = (const float*)d_in[0];
    const float* xn  = (const float*)d_in[1];
    const float* ew  = (const float*)d_in[2];
    const float* gl  = (const float*)d_in[3];
    const float* Wa  = (const float*)d_in[4];
    const float* ba  = (const float*)d_in[5];
    const float* ga  = (const float*)d_in[6];
    const float* bea = (const float*)d_in[7];
    const float* Wn  = (const float*)d_in[8];
    const float* bn  = (const float*)d_in[9];
    const float* gn  = (const float*)d_in[10];
    const float* ben = (const float*)d_in[11];
    const float* ve  = (const float*)d_in[12];
    const float* Wq  = (const float*)d_in[13];
    const float* Wk  = (const float*)d_in[14];
    const float* Wv  = (const float*)d_in[15];
    const float* Wo  = (const float*)d_in[16];
    const float* Wg  = (const float*)d_in[17];
    const float* bg  = (const float*)d_in[18];
    int B = in_sizes[0] / 256;

    char* ws = (char*)d_ws;
    u16* WnB  = (u16*)(ws + 0);
    u16* WaB  = (u16*)(ws + 131072);
    u16* WqF  = (u16*)(ws + 262144);
    u16* WkF  = (u16*)(ws + 278528);
    float* ha   = (float*)(ws + 294912);
    float* qws  = (float*)(ws + 294912 + 8388608);
    float* gsws = (float*)(ws + 294912 + 16777216);
    float* outp = (float*)d_out;

    hipLaunchKernelGGL(k_prep, dim3(256), dim3(256), 0, stream,
                       Wa, Wn, Wq, Wk, WaB, WnB, WqF, WkF);
    hipLaunchKernelGGL(k_anchor, dim3(B/64), dim3(256), 0, stream,
                       xa, gl, ba, ga, bea, ve, Wg, bg, WaB, WqF, ha, qws, gsws);
    hipLaunchKernelGGL(k_main, dim3(B), dim3(256), 0, stream,
                       xn, ew, bn, gn, ben, Wv, Wo, WnB, WkF, ha, qws, gsws, outp, B);
}